// Round 4
// baseline (193.644 us; speedup 1.0000x reference)
//
#include <hip/hip_runtime.h>

typedef __attribute__((ext_vector_type(8))) short short8;
typedef __attribute__((ext_vector_type(4))) float f32x4;

#define CM 256
#define CC 32
#define CZ 128
#define SDIM 128
#define IDIM 256

__device__ __forceinline__ unsigned short f2bf(float f) {
  union { float f; unsigned u; } v; v.f = f;
  unsigned r = v.u + 0x7fffu + ((v.u >> 16) & 1u);
  return (unsigned short)(r >> 16);
}
// pack two f32 -> two bf16 (round-half-up)
__device__ __forceinline__ unsigned pack_bf2(float a, float b) {
  union { float f; unsigned u; } x, y; x.f = a; y.f = b;
  return ((x.u + 0x8000u) >> 16) | ((y.u + 0x8000u) & 0xffff0000u);
}

// ---------------- kernel 0: weight prep ---------------- (unchanged)
__global__ void k_prep(const float* __restrict__ wl, const float* __restrict__ wr,
                       const float* __restrict__ wo,
                       unsigned short* __restrict__ wlrT2, unsigned short* __restrict__ WF) {
  int t = blockIdx.x * 256 + threadIdx.x;
  if (t < 2048) {
    int frag = t >> 6, lane = t & 63;
    int nt = frag >> 3, ks = frag & 7;
    int ln = lane & 15, qd = lane >> 4;
    int c64 = nt * 16 + ln;
#pragma unroll
    for (int e = 0; e < 8; ++e) {
      int cm = ks * 32 + qd * 8 + e;
      float v = (c64 < CC) ? wl[cm * CC + c64] : wr[cm * CC + (c64 - CC)];
      wlrT2[(size_t)t * 8 + e] = f2bf(v);
    }
  } else {
    int t2 = t - 2048;
    if (t2 < 8 * 32 * 64) {
      int zt = t2 >> 11, ks = (t2 >> 6) & 31, lane = t2 & 63;
      int ln = lane & 15, qd = lane >> 4;
      int z = zt * 16 + ln;
#pragma unroll
      for (int e = 0; e < 8; ++e) {
        int c = qd * 8 + e, d = ks;
        WF[(size_t)t2 * 8 + e] = f2bf(wo[(c * 32 + d) * CZ + z] * (1.0f / 128.0f));
      }
    }
  }
}

// ---------------- kernel 1: LayerNorm + dual projection ---------------- (unchanged)
__global__ __launch_bounds__(256) void k_lnproj(
    const float* __restrict__ x, const float* __restrict__ lnw, const float* __restrict__ lnb,
    const float* __restrict__ bl, const float* __restrict__ br,
    const unsigned short* __restrict__ wlrT2,
    unsigned short* __restrict__ A2, unsigned short* __restrict__ Bbuf) {
  __shared__ __align__(16) unsigned short xn[64][264];
  __shared__ __align__(16) unsigned short sT[64][72];
  int tid = threadIdx.x;
  int lane = tid & 63, ww = tid >> 6;
  int qd = lane >> 4, ln = lane & 15;
  int i = blockIdx.x, sh = blockIdx.y;

  for (int rr = 0; rr < 16; ++rr) {
    int sl = ww * 16 + rr;
    int s = sh * 64 + sl;
    float4 v = ((const float4*)(x + ((size_t)s * IDIM + i) * CM))[lane];
    float s1 = v.x + v.y + v.z + v.w;
    float s2 = v.x * v.x + v.y * v.y + v.z * v.z + v.w * v.w;
#pragma unroll
    for (int off = 32; off; off >>= 1) {
      s1 += __shfl_xor(s1, off);
      s2 += __shfl_xor(s2, off);
    }
    float mu = s1 * (1.0f / 256.0f);
    float var = s2 * (1.0f / 256.0f) - mu * mu;
    float rs = rsqrtf(var + 1e-5f);
    float4 w4 = ((const float4*)lnw)[lane];
    float4 b4 = ((const float4*)lnb)[lane];
    ushort4 h;
    h.x = f2bf((v.x - mu) * rs * w4.x + b4.x);
    h.y = f2bf((v.y - mu) * rs * w4.y + b4.y);
    h.z = f2bf((v.z - mu) * rs * w4.z + b4.z);
    h.w = f2bf((v.w - mu) * rs * w4.w + b4.w);
    *(ushort4*)&xn[sl][lane * 4] = h;
  }
  __syncthreads();

  f32x4 acc[4];
#pragma unroll
  for (int nt = 0; nt < 4; ++nt) acc[nt] = (f32x4){0.f, 0.f, 0.f, 0.f};
#pragma unroll
  for (int ks = 0; ks < 8; ++ks) {
    short8 af = *(const short8*)&xn[ww * 16 + ln][ks * 32 + qd * 8];
#pragma unroll
    for (int nt = 0; nt < 4; ++nt) {
      short8 bf = *(const short8*)(wlrT2 + ((size_t)((nt * 8 + ks) * 64 + lane)) * 8);
      acc[nt] = __builtin_amdgcn_mfma_f32_16x16x32_bf16(af, bf, acc[nt], 0, 0, 0);
    }
  }
#pragma unroll
  for (int nt = 0; nt < 4; ++nt) {
    int c64 = nt * 16 + ln;
    float bias = (c64 < CC) ? bl[c64] : br[c64 - CC];
    ushort4 h;
    h.x = f2bf(acc[nt][0] + bias);
    h.y = f2bf(acc[nt][1] + bias);
    h.z = f2bf(acc[nt][2] + bias);
    h.w = f2bf(acc[nt][3] + bias);
    *(ushort4*)&sT[c64][ww * 16 + qd * 4] = h;
  }
  __syncthreads();

  {
    int rtloc = ww >> 1, ksl = ww & 1;
    short8 v = *(const short8*)&sT[rtloc * 16 + ln][ksl * 32 + qd * 8];
    *(short8*)(A2 + ((size_t)(((2 * i + rtloc) * 4 + (sh * 2 + ksl)) * 64 + lane)) * 8) = v;
  }
  {
    int row = tid >> 3, ch = tid & 7;
    short8 v = *(const short8*)&sT[CC + row][ch * 8];
    *(short8*)(Bbuf + ((size_t)(i * CC + row)) * SDIM + sh * 64 + ch * 8) = v;
  }
}

// ---------------- kernel 2 (v5): v4 structure with CORRECT register budget ----
// __launch_bounds__ 2nd arg is CUDA-style min-BLOCKS-per-CU on hipcc (measured here:
// (512,4)->64-cap r2, (512,2)->128-cap r3). (512,1) -> 8 waves/CU = 2 waves/SIMD ->
// 256 VGPR/wave cap. Peak live ~180-200 (afA 64 + acc1 64 + bpre 32 + temps): fits.
// Grid = 256 blocks x 512 threads (8 waves). Block owns i0 = itile*8 (XCD-affine)
// and walks 4 j-tiles of 8 j each (64 pairs/tile). A2 register-pinned (read once);
// WF streamed from L2 (256 KB/tile-loop, halved vs 32-pair tiles); B prefetched
// global->reg during p2 of the previous tile (T14).
// LDS (163,840 B exactly, 1 block/CU):
//   sP  [64][1032] shorts -> bytes [0, 132,096)
//   sB  [256][136] shorts -> bytes [94,208, 163,840)   (TOP of LDS)
//   redR 32 KB f32        -> bytes [0, 32,768)   (overlay on sP rows 0..15)
// Overlap hazards (sP rows 32..63 overlap sB rows 0..139):
//   p1 runs in two col-halves h=0,1 (wxx = h*2+wx), reusing acc1[4][4]:
//     h0: reads sB rows 0..127;  P-write rows [0,32) = bytes [0,66,048) -- disjoint from sB.
//     h1: reads sB rows 128..255; MID-BARRIER; P-write rows [32,64) may clobber sB.
//   Next tile's B-write overlaps sP rows 46..63: p2 reads drained at post-p2 barrier.
//   Next tile's h0 P-write overlaps redR: kq0's redR reads drained at post-Bwrite barrier.
// Barriers: 5/tile.
__global__ __launch_bounds__(512, 1) void k_main(
    const unsigned short* __restrict__ A2, const unsigned short* __restrict__ Bbuf,
    const unsigned short* __restrict__ WF, const float* __restrict__ bout,
    float* __restrict__ out) {
  extern __shared__ __align__(16) char lds[];
  unsigned short* sP = (unsigned short*)lds;             // [64][1032]
  unsigned short* sB = (unsigned short*)(lds + 94208);   // [256][136]
  float* redR = (float*)lds;                             // 32 slots x 1 KB
  int tid = threadIdx.x;
  int lane = tid & 63, ww = tid >> 6;  // 8 waves
  int qd = lane >> 4, ln = lane & 15;
  int bx = blockIdx.x;
  int itile = (bx & 7) * 4 + ((bx >> 3) & 3);  // XCD-affine i-tile
  int jg = bx >> 5;                            // j-group: tiles jg*4 .. +3
  int i0 = itile * 8;
  int wy = ww >> 1, wx = ww & 1;               // p1 wave coords (4 x 2)
  int ztp = ww & 3, kq = ww >> 2;              // p2 wave coords (4 x 2)

  short8 afA[16];  // pinned A-fragments [ti*4+ks]
  short8 bpre[8];  // B staging registers (dead during p1)

  // ---- prologue: issue B(0) loads; pin afA ----
#pragma unroll
  for (int tt = 0; tt < 8; ++tt) {
    int idx = tid + tt * 512;
    int r = idx >> 4, ch = idx & 15;
    bpre[tt] = *(const short8*)(Bbuf + ((size_t)(jg * 4) * 256 + r) * SDIM + ch * 8);
  }
#pragma unroll
  for (int ti = 0; ti < 4; ++ti)
#pragma unroll
    for (int ks = 0; ks < 4; ++ks)
      afA[ti * 4 + ks] =
          *(const short8*)(A2 + ((size_t)((i0 * 2 + wy * 4 + ti) * 4 + ks) * 64 + lane) * 8);

  for (int t = 0; t < 4; ++t) {
    int j0 = (jg * 4 + t) * 8;

    // ---- B stage: bpre -> sB (vmcnt wait inserted by compiler) ----
#pragma unroll
    for (int tt = 0; tt < 8; ++tt) {
      int idx = tid + tt * 512;
      int r = idx >> 4, ch = idx & 15;
      *(short8*)&sB[r * 136 + ch * 8] = bpre[tt];
    }
    __syncthreads();

    // ---- phase 1: P[256 rows][256 cols] = A @ B^T in two col-halves ----
#pragma unroll
    for (int h = 0; h < 2; ++h) {
      int wxx = h * 2 + wx;  // col-tile group [0,4); h0 -> sB rows <128, h1 -> >=128
      f32x4 acc1[4][4];
#pragma unroll
      for (int a = 0; a < 4; ++a)
#pragma unroll
        for (int b = 0; b < 4; ++b) acc1[a][b] = (f32x4){0.f, 0.f, 0.f, 0.f};
#pragma unroll
      for (int ks = 0; ks < 4; ++ks)
#pragma unroll
        for (int tj = 0; tj < 4; ++tj) {
          short8 bf = *(const short8*)&sB[((wxx * 4 + tj) * 16 + ln) * 136 + ks * 32 + qd * 8];
#pragma unroll
          for (int ti = 0; ti < 4; ++ti)
            acc1[ti][tj] =
                __builtin_amdgcn_mfma_f32_16x16x32_bf16(afA[ti * 4 + ks], bf, acc1[ti][tj], 0, 0, 0);
        }
      if (h == 1) __syncthreads();  // all sB reads done before h1 P-writes clobber sB
      // P-write: p = h*32 + iloc*4 + jl2; kappa offset d*32 + swizzle
#pragma unroll
      for (int ti = 0; ti < 4; ++ti) {
        int iloc = wy * 2 + (ti >> 1);
        int cbase = 16 * (ti & 1) + qd * 4;
        int cb = cbase >> 3;
#pragma unroll
        for (int tj = 0; tj < 4; ++tj) {
          int jl2 = wx * 2 + (tj >> 1);
          int d = 16 * (tj & 1) + ln;
          int p = h * 32 + iloc * 4 + jl2;
          uint2 u;
          u.x = pack_bf2(acc1[ti][tj][0], acc1[ti][tj][1]);
          u.y = pack_bf2(acc1[ti][tj][2], acc1[ti][tj][3]);
          *(uint2*)&sP[p * 1032 + d * 32 + ((((d >> 1) & 3) ^ cb) * 8) + (cbase & 7)] = u;
        }
      }
    }
    __syncthreads();

    // ---- issue B(t+1) global->reg early (hidden under p2) ----
    if (t < 3) {
#pragma unroll
      for (int tt = 0; tt < 8; ++tt) {
        int idx = tid + tt * 512;
        int r = idx >> 4, ch = idx & 15;
        bpre[tt] = *(const short8*)(Bbuf + ((size_t)(jg * 4 + t + 1) * 256 + r) * SDIM + ch * 8);
      }
    }

    // ---- phase 2: operand-swapped mfma(W, P); WF streamed from L2 ----
    f32x4 acc2[2][4];  // [h2][mt]
#pragma unroll
    for (int a = 0; a < 2; ++a)
#pragma unroll
      for (int b = 0; b < 4; ++b) acc2[a][b] = (f32x4){0.f, 0.f, 0.f, 0.f};
#pragma unroll
    for (int cc = 0; cc < 16; ++cc) {
      int ks = kq * 16 + cc;
      short8 afr[4];
#pragma unroll
      for (int mt = 0; mt < 4; ++mt)
        afr[mt] =
            *(const short8*)&sP[(mt * 16 + ln) * 1032 + ks * 32 + ((((ks >> 1) & 3) ^ qd) * 8)];
#pragma unroll
      for (int h2 = 0; h2 < 2; ++h2) {
        int zt = ztp * 2 + h2;
        short8 bfr = *(const short8*)(WF + ((size_t)(zt * 32 + ks) * 64 + lane) * 8);
#pragma unroll
        for (int mt = 0; mt < 4; ++mt)  // SWAPPED: D[m=z][n=p]
          acc2[h2][mt] =
              __builtin_amdgcn_mfma_f32_16x16x32_bf16(bfr, afr[mt], acc2[h2][mt], 0, 0, 0);
      }
    }
    __syncthreads();  // all sP reads done -> redR overlay + next B-write safe

    // ---- kq 2-way reduction via lane-linear redR slots ----
    if (kq == 1) {
#pragma unroll
      for (int h2 = 0; h2 < 2; ++h2)
#pragma unroll
        for (int mt = 0; mt < 4; ++mt)
          *(f32x4*)&redR[(((ztp * 2 + h2) * 4 + mt) << 8) + lane * 4] = acc2[h2][mt];
    }
    __syncthreads();
    if (kq == 0) {
#pragma unroll
      for (int h2 = 0; h2 < 2; ++h2) {
        int z = (ztp * 2 + h2) * 16 + qd * 4;
        f32x4 bz = *(const f32x4*)(bout + z);
#pragma unroll
        for (int mt = 0; mt < 4; ++mt) {
          int p = mt * 16 + ln;
          f32x4 v = acc2[h2][mt] +
                    *(const f32x4*)&redR[(((ztp * 2 + h2) * 4 + mt) << 8) + lane * 4] + bz;
          int i = i0 + ((p >> 2) & 7), j = j0 + (p >> 5) * 4 + (p & 3);
          *(f32x4*)&out[((size_t)i * IDIM + j) * CZ + z] = v;
        }
      }
    }
  }
}

extern "C" void kernel_launch(void* const* d_in, const int* in_sizes, int n_in,
                              void* d_out, int out_size, void* d_ws, size_t ws_size,
                              hipStream_t stream) {
  const float* msa = (const float*)d_in[0];
  const float* lnw = (const float*)d_in[1];
  const float* lnb = (const float*)d_in[2];
  const float* wl  = (const float*)d_in[3];
  const float* bl  = (const float*)d_in[4];
  const float* wr  = (const float*)d_in[5];
  const float* br  = (const float*)d_in[6];
  const float* wo  = (const float*)d_in[7];
  const float* bo  = (const float*)d_in[8];
  float* out = (float*)d_out;

  char* ws = (char*)d_ws;
  unsigned short* A2    = (unsigned short*)ws;                         // 2 MB (frag-major)
  unsigned short* Bbuf  = (unsigned short*)(ws + (2u << 20));          // 2 MB (row-major)
  unsigned short* wlrT2 = (unsigned short*)(ws + (4u << 20));          // 32 KB (frag-major)
  unsigned short* WF    = (unsigned short*)(ws + (4u << 20) + 32768);  // 256 KB

  (void)hipFuncSetAttribute((const void*)k_main,
                            hipFuncAttributeMaxDynamicSharedMemorySize, 163840);

  k_prep<<<72, 256, 0, stream>>>(wl, wr, wo, wlrT2, WF);
  k_lnproj<<<dim3(256, 2), 256, 0, stream>>>(msa, lnw, lnb, bl, br, wlrT2, A2, Bbuf);
  k_main<<<256, 512, 163840, stream>>>(A2, Bbuf, WF, bo, out);
}

// Round 5
// 143.734 us; speedup vs baseline: 1.3472x; 1.3472x over previous
//
#include <hip/hip_runtime.h>

typedef __attribute__((ext_vector_type(8))) short short8;
typedef __attribute__((ext_vector_type(4))) float f32x4;

#define CM 256
#define CC 32
#define CZ 128
#define SDIM 128
#define IDIM 256

__device__ __forceinline__ unsigned short f2bf(float f) {
  union { float f; unsigned u; } v; v.f = f;
  unsigned r = v.u + 0x7fffu + ((v.u >> 16) & 1u);
  return (unsigned short)(r >> 16);
}
// pack two f32 -> two bf16 (round-half-up)
__device__ __forceinline__ unsigned pack_bf2(float a, float b) {
  union { float f; unsigned u; } x, y; x.f = a; y.f = b;
  return ((x.u + 0x8000u) >> 16) | ((y.u + 0x8000u) & 0xffff0000u);
}

// ---------------- kernel 0: weight prep ---------------- (unchanged)
__global__ void k_prep(const float* __restrict__ wl, const float* __restrict__ wr,
                       const float* __restrict__ wo,
                       unsigned short* __restrict__ wlrT2, unsigned short* __restrict__ WF) {
  int t = blockIdx.x * 256 + threadIdx.x;
  if (t < 2048) {
    int frag = t >> 6, lane = t & 63;
    int nt = frag >> 3, ks = frag & 7;
    int ln = lane & 15, qd = lane >> 4;
    int c64 = nt * 16 + ln;
#pragma unroll
    for (int e = 0; e < 8; ++e) {
      int cm = ks * 32 + qd * 8 + e;
      float v = (c64 < CC) ? wl[cm * CC + c64] : wr[cm * CC + (c64 - CC)];
      wlrT2[(size_t)t * 8 + e] = f2bf(v);
    }
  } else {
    int t2 = t - 2048;
    if (t2 < 8 * 32 * 64) {
      int zt = t2 >> 11, ks = (t2 >> 6) & 31, lane = t2 & 63;
      int ln = lane & 15, qd = lane >> 4;
      int z = zt * 16 + ln;
#pragma unroll
      for (int e = 0; e < 8; ++e) {
        int c = qd * 8 + e, d = ks;
        WF[(size_t)t2 * 8 + e] = f2bf(wo[(c * 32 + d) * CZ + z] * (1.0f / 128.0f));
      }
    }
  }
}

// ---------------- kernel 1: LayerNorm + dual projection ---------------- (unchanged)
__global__ __launch_bounds__(256) void k_lnproj(
    const float* __restrict__ x, const float* __restrict__ lnw, const float* __restrict__ lnb,
    const float* __restrict__ bl, const float* __restrict__ br,
    const unsigned short* __restrict__ wlrT2,
    unsigned short* __restrict__ A2, unsigned short* __restrict__ Bbuf) {
  __shared__ __align__(16) unsigned short xn[64][264];
  __shared__ __align__(16) unsigned short sT[64][72];
  int tid = threadIdx.x;
  int lane = tid & 63, ww = tid >> 6;
  int qd = lane >> 4, ln = lane & 15;
  int i = blockIdx.x, sh = blockIdx.y;

  for (int rr = 0; rr < 16; ++rr) {
    int sl = ww * 16 + rr;
    int s = sh * 64 + sl;
    float4 v = ((const float4*)(x + ((size_t)s * IDIM + i) * CM))[lane];
    float s1 = v.x + v.y + v.z + v.w;
    float s2 = v.x * v.x + v.y * v.y + v.z * v.z + v.w * v.w;
#pragma unroll
    for (int off = 32; off; off >>= 1) {
      s1 += __shfl_xor(s1, off);
      s2 += __shfl_xor(s2, off);
    }
    float mu = s1 * (1.0f / 256.0f);
    float var = s2 * (1.0f / 256.0f) - mu * mu;
    float rs = rsqrtf(var + 1e-5f);
    float4 w4 = ((const float4*)lnw)[lane];
    float4 b4 = ((const float4*)lnb)[lane];
    ushort4 h;
    h.x = f2bf((v.x - mu) * rs * w4.x + b4.x);
    h.y = f2bf((v.y - mu) * rs * w4.y + b4.y);
    h.z = f2bf((v.z - mu) * rs * w4.z + b4.z);
    h.w = f2bf((v.w - mu) * rs * w4.w + b4.w);
    *(ushort4*)&xn[sl][lane * 4] = h;
  }
  __syncthreads();

  f32x4 acc[4];
#pragma unroll
  for (int nt = 0; nt < 4; ++nt) acc[nt] = (f32x4){0.f, 0.f, 0.f, 0.f};
#pragma unroll
  for (int ks = 0; ks < 8; ++ks) {
    short8 af = *(const short8*)&xn[ww * 16 + ln][ks * 32 + qd * 8];
#pragma unroll
    for (int nt = 0; nt < 4; ++nt) {
      short8 bf = *(const short8*)(wlrT2 + ((size_t)((nt * 8 + ks) * 64 + lane)) * 8);
      acc[nt] = __builtin_amdgcn_mfma_f32_16x16x32_bf16(af, bf, acc[nt], 0, 0, 0);
    }
  }
#pragma unroll
  for (int nt = 0; nt < 4; ++nt) {
    int c64 = nt * 16 + ln;
    float bias = (c64 < CC) ? bl[c64] : br[c64 - CC];
    ushort4 h;
    h.x = f2bf(acc[nt][0] + bias);
    h.y = f2bf(acc[nt][1] + bias);
    h.z = f2bf(acc[nt][2] + bias);
    h.w = f2bf(acc[nt][3] + bias);
    *(ushort4*)&sT[c64][ww * 16 + qd * 4] = h;
  }
  __syncthreads();

  {
    int rtloc = ww >> 1, ksl = ww & 1;
    short8 v = *(const short8*)&sT[rtloc * 16 + ln][ksl * 32 + qd * 8];
    *(short8*)(A2 + ((size_t)(((2 * i + rtloc) * 4 + (sh * 2 + ksl)) * 64 + lane)) * 8) = v;
  }
  {
    int row = tid >> 3, ch = tid & 7;
    short8 v = *(const short8*)&sT[CC + row][ch * 8];
    *(short8*)(Bbuf + ((size_t)(i * CC + row)) * SDIM + sh * 64 + ch * 8) = v;
  }
}

// ---------------- kernel 2 (v6): dual-P-buffer, WF-shared p2, 128-VGPR-honest ----
// 1024 blocks x 512 threads (8 waves). Block = i0 (8 i) x 8 j = 64 pairs, processed as
// two 32-pair tiles (tb 0,1) whose P-buffers BOTH stay resident; ONE p2 pass reads each
// WF fragment once and applies it to both tiles -> WF L2 traffic 512->256 MB.
// p1 wave map wy8 x wx1: each wave owns P-rows [ww*32,+32) -> only 8 A-frags/wave,
// PINNED in 32 VGPR (fits the observed 128-cap; r3's 64-frag pinning did not).
// A2 L2 traffic 256->64 MB. B staged in 64-row halves (sB 17 KB; 4 stages/block).
// LDS (149,504 B, all regions DISJOINT -- no overlay hazards):
//   sPA [32][1032] sh = 66,048  @ 0
//   sPB [32][1032] sh = 66,048  @ 66,048
//   sB  [64][136]  sh = 17,408  @ 132,096
//   redR 32 KB f32 overlays sPA only AFTER the post-p2 barrier.
// Quarters q=0..3: buffer tb=q>>1, B-half h=q&1 (tile-local j = 2h+(tjj>>1)).
// Per q: {stage sB, bar, issue bpre(q+1), p1-pass, bar, P-write}. P-writes (to sP*)
// are concurrent-safe with next stage (disjoint); all P visible at the pre-p2 barrier.
__global__ __launch_bounds__(512, 2) void k_main(
    const unsigned short* __restrict__ A2, const unsigned short* __restrict__ Bbuf,
    const unsigned short* __restrict__ WF, const float* __restrict__ bout,
    float* __restrict__ out) {
  extern __shared__ __align__(16) char lds[];
  unsigned short* sPA = (unsigned short*)lds;              // [32][1032]
  unsigned short* sPB = (unsigned short*)(lds + 66048);    // [32][1032]
  unsigned short* sB  = (unsigned short*)(lds + 132096);   // [64][136]
  float* redR = (float*)lds;                               // 32 slots x 1 KB (post-p2)
  int tid = threadIdx.x;
  int lane = tid & 63, ww = tid >> 6;  // 8 waves
  int qd = lane >> 4, ln = lane & 15;
  int bx = blockIdx.x;
  int itile = (bx & 7) * 4 + ((bx >> 3) & 3);  // XCD-affine i-tile (0..31)
  int jg = bx >> 5;                            // j-group (0..31): j = jg*8 .. +7
  int i0 = itile * 8;
  int ztp = ww & 3, kq = ww >> 2;              // p2 wave coords (4 x 2)

  // ---- pinned A-fragments: wave ww owns P-row-tiles rt = i0*2 + ww*2 + ti ----
  short8 afp[2][4];  // [ti][ks] = 8 frags = 32 VGPR
#pragma unroll
  for (int ti = 0; ti < 2; ++ti)
#pragma unroll
    for (int ks = 0; ks < 4; ++ks)
      afp[ti][ks] =
          *(const short8*)(A2 + ((size_t)((i0 * 2 + ww * 2 + ti) * 4 + ks) * 64 + lane) * 8);

  short8 bpre[2];  // B half-tile staging (64 rows x 16 chunks / 512 thr)
#pragma unroll
  for (int tt = 0; tt < 2; ++tt) {
    int idx = tid + tt * 512;
    int r = idx >> 4, ch = idx & 15;
    bpre[tt] = *(const short8*)(Bbuf + ((size_t)(jg * 256 + r)) * SDIM + ch * 8);
  }

#pragma unroll
  for (int q = 0; q < 4; ++q) {
    // ---- stage current B half ----
#pragma unroll
    for (int tt = 0; tt < 2; ++tt) {
      int idx = tid + tt * 512;
      int r = idx >> 4, ch = idx & 15;
      *(short8*)&sB[r * 136 + ch * 8] = bpre[tt];
    }
    __syncthreads();
    // ---- issue next half's loads (hidden under p1) ----
    if (q < 3) {
#pragma unroll
      for (int tt = 0; tt < 2; ++tt) {
        int idx = tid + tt * 512;
        int r = idx >> 4, ch = idx & 15;
        bpre[tt] = *(const short8*)(Bbuf + ((size_t)(jg * 256 + (q + 1) * 64 + r)) * SDIM + ch * 8);
      }
    }
    // ---- p1 pass: P[rows ww*32..+32][64 staged cols] ----
    unsigned short* sP = (q & 2) ? sPB : sPA;
    f32x4 acc1[2][4];
#pragma unroll
    for (int a = 0; a < 2; ++a)
#pragma unroll
      for (int b = 0; b < 4; ++b) acc1[a][b] = (f32x4){0.f, 0.f, 0.f, 0.f};
#pragma unroll
    for (int ks = 0; ks < 4; ++ks)
#pragma unroll
      for (int tjj = 0; tjj < 4; ++tjj) {
        short8 bf = *(const short8*)&sB[(tjj * 16 + ln) * 136 + ks * 32 + qd * 8];
#pragma unroll
        for (int ti = 0; ti < 2; ++ti)
          acc1[ti][tjj] =
              __builtin_amdgcn_mfma_f32_16x16x32_bf16(afp[ti][ks], bf, acc1[ti][tjj], 0, 0, 0);
      }
    __syncthreads();  // all sB reads done -> next stage safe
    // ---- P-write (disjoint from sB; visible at pre-p2 barrier) ----
#pragma unroll
    for (int ti = 0; ti < 2; ++ti) {
      int cbase = 16 * ti + qd * 4;
      int cb = cbase >> 3;
#pragma unroll
      for (int tjj = 0; tjj < 4; ++tjj) {
        int d = 16 * (tjj & 1) + ln;
        int p = ww * 4 + 2 * (q & 1) + (tjj >> 1);  // pair = i_loc*4 + tile-local j
        uint2 u;
        u.x = pack_bf2(acc1[ti][tjj][0], acc1[ti][tjj][1]);
        u.y = pack_bf2(acc1[ti][tjj][2], acc1[ti][tjj][3]);
        *(uint2*)&sP[p * 1032 + d * 32 + ((((d >> 1) & 3) ^ cb) * 8) + (cbase & 7)] = u;
      }
    }
  }
  __syncthreads();  // all P-writes visible

  // ---- p2: operand-swapped mfma(W, P), each WF fragment applied to BOTH buffers ----
  f32x4 acc2[2][2][2];  // [tb][h2][mt]
#pragma unroll
  for (int a = 0; a < 2; ++a)
#pragma unroll
    for (int b = 0; b < 2; ++b)
#pragma unroll
      for (int c = 0; c < 2; ++c) acc2[a][b][c] = (f32x4){0.f, 0.f, 0.f, 0.f};
#pragma unroll
  for (int cc = 0; cc < 16; ++cc) {
    int ks = kq * 16 + cc;
    int swz = ((((ks >> 1) & 3) ^ qd) * 8);
    short8 afr[2][2];  // [tb][mt]
#pragma unroll
    for (int mt = 0; mt < 2; ++mt) {
      afr[0][mt] = *(const short8*)&sPA[(mt * 16 + ln) * 1032 + ks * 32 + swz];
      afr[1][mt] = *(const short8*)&sPB[(mt * 16 + ln) * 1032 + ks * 32 + swz];
    }
#pragma unroll
    for (int h2 = 0; h2 < 2; ++h2) {
      int zt = ztp * 2 + h2;
      short8 bfr = *(const short8*)(WF + ((size_t)(zt * 32 + ks) * 64 + lane) * 8);
#pragma unroll
      for (int tb = 0; tb < 2; ++tb)
#pragma unroll
        for (int mt = 0; mt < 2; ++mt)  // SWAPPED: D[m=z][n=p]
          acc2[tb][h2][mt] = __builtin_amdgcn_mfma_f32_16x16x32_bf16(bfr, afr[tb][mt],
                                                                    acc2[tb][h2][mt], 0, 0, 0);
    }
  }
  __syncthreads();  // all sP reads done -> redR overlay safe

  // ---- kq 2-way reduction via lane-linear redR slots (32 x 1KB) ----
  if (kq == 1) {
#pragma unroll
    for (int tb = 0; tb < 2; ++tb)
#pragma unroll
      for (int h2 = 0; h2 < 2; ++h2)
#pragma unroll
        for (int mt = 0; mt < 2; ++mt)
          *(f32x4*)&redR[((((tb * 4 + ztp) * 2 + h2) * 2 + mt) << 8) + lane * 4] =
              acc2[tb][h2][mt];
  }
  __syncthreads();
  if (kq == 0) {
#pragma unroll
    for (int tb = 0; tb < 2; ++tb)
#pragma unroll
      for (int h2 = 0; h2 < 2; ++h2) {
        int z = (ztp * 2 + h2) * 16 + qd * 4;
        f32x4 bz = *(const f32x4*)(bout + z);
#pragma unroll
        for (int mt = 0; mt < 2; ++mt) {
          int p = mt * 16 + ln;
          f32x4 v = acc2[tb][h2][mt] +
                    *(const f32x4*)&redR[((((tb * 4 + ztp) * 2 + h2) * 2 + mt) << 8) + lane * 4] +
                    bz;
          int i = i0 + (p >> 2), j = jg * 8 + tb * 4 + (p & 3);
          *(f32x4*)&out[((size_t)i * IDIM + j) * CZ + z] = v;
        }
      }
  }
}

extern "C" void kernel_launch(void* const* d_in, const int* in_sizes, int n_in,
                              void* d_out, int out_size, void* d_ws, size_t ws_size,
                              hipStream_t stream) {
  const float* msa = (const float*)d_in[0];
  const float* lnw = (const float*)d_in[1];
  const float* lnb = (const float*)d_in[2];
  const float* wl  = (const float*)d_in[3];
  const float* bl  = (const float*)d_in[4];
  const float* wr  = (const float*)d_in[5];
  const float* br  = (const float*)d_in[6];
  const float* wo  = (const float*)d_in[7];
  const float* bo  = (const float*)d_in[8];
  float* out = (float*)d_out;

  char* ws = (char*)d_ws;
  unsigned short* A2    = (unsigned short*)ws;                         // 2 MB (frag-major)
  unsigned short* Bbuf  = (unsigned short*)(ws + (2u << 20));          // 2 MB (row-major)
  unsigned short* wlrT2 = (unsigned short*)(ws + (4u << 20));          // 32 KB (frag-major)
  unsigned short* WF    = (unsigned short*)(ws + (4u << 20) + 32768);  // 256 KB

  (void)hipFuncSetAttribute((const void*)k_main,
                            hipFuncAttributeMaxDynamicSharedMemorySize, 149504);

  k_prep<<<72, 256, 0, stream>>>(wl, wr, wo, wlrT2, WF);
  k_lnproj<<<dim3(256, 2), 256, 0, stream>>>(msa, lnw, lnb, bl, br, wlrT2, A2, Bbuf);
  k_main<<<1024, 512, 149504, stream>>>(A2, Bbuf, WF, bo, out);
}